// Round 1
// baseline (893.471 us; speedup 1.0000x reference)
//
#include <hip/hip_runtime.h>

#define NN 50000
#define NE 800000
#define D  128

// ---------------- CSR build ----------------

__global__ void count_deg(const int* __restrict__ row, int* __restrict__ deg, int e) {
    int i = blockIdx.x * blockDim.x + threadIdx.x;
    if (i < e) atomicAdd(&deg[row[i]], 1);
}

// Single-block chunked Hillis-Steele scan over 50000 degrees.
__global__ void scan_offsets(const int* __restrict__ deg, int* __restrict__ offsets,
                             int* __restrict__ cursor, int n) {
    __shared__ int s[1024];
    int carry = 0;
    for (int base = 0; base < n; base += 1024) {
        int i = base + (int)threadIdx.x;
        int v = (i < n) ? deg[i] : 0;
        s[threadIdx.x] = v;
        __syncthreads();
        for (int off = 1; off < 1024; off <<= 1) {
            int t = (threadIdx.x >= (unsigned)off) ? s[threadIdx.x - off] : 0;
            __syncthreads();
            s[threadIdx.x] += t;
            __syncthreads();
        }
        int incl = s[threadIdx.x];
        if (i < n) {
            offsets[i + 1] = carry + incl;       // inclusive -> offsets[i+1]
            cursor[i]      = carry + incl - v;   // exclusive -> fill cursor
        }
        int total = s[1023];
        __syncthreads();                          // protect s[] before next chunk
        carry += total;
    }
    if (threadIdx.x == 0) offsets[0] = 0;
}

__global__ void fill_csr(const int* __restrict__ row, const int* __restrict__ col,
                         int* __restrict__ cursor, int* __restrict__ csr_col, int e) {
    int i = blockIdx.x * blockDim.x + threadIdx.x;
    if (i < e) {
        int p = atomicAdd(&cursor[row[i]], 1);
        csr_col[p] = col[i];
    }
}

// ---------------- mean aggregation (gather over CSR) ----------------
// One 64-lane wave per node; lane t holds features [2t, 2t+1] (float2 -> 512B
// coalesced per gathered row). No intra-wave divergence (single node per wave).
__global__ __launch_bounds__(256) void aggregate(
    const float* __restrict__ h, const int* __restrict__ offsets,
    const int* __restrict__ csr_col, float* __restrict__ agg, int relu_in) {
    int node = blockIdx.x * 4 + (threadIdx.x >> 6);
    int t = threadIdx.x & 63;
    if (node >= NN) return;
    int s0 = offsets[node], e0 = offsets[node + 1];
    float2 acc = make_float2(0.f, 0.f);
    for (int j = s0; j < e0; ++j) {
        int c = csr_col[j];
        float2 v = *((const float2*)(h + (size_t)c * D) + t);
        if (relu_in) { v.x = fmaxf(v.x, 0.f); v.y = fmaxf(v.y, 0.f); }
        acc.x += v.x; acc.y += v.y;
    }
    float inv = 1.f / fmaxf((float)(e0 - s0), 1.f);
    acc.x *= inv; acc.y *= inv;
    *((float2*)(agg + (size_t)node * D) + t) = acc;
}

// ---------------- fused dual-GEMM + bias + residual ----------------
// out[n][o] = sum_k agg[n][k]*Wl[o][k] + relu?(hsrc[n][k])*Wr[o][k] + b[o] (+ hsrc[n][o])
// Block: 256 threads, tile 64 rows x 128 cols. K chunked by 32, k-major LDS.
// Strides: sA/sX 68 floats (68%32=4 -> ty-quad reads hit distinct bank groups),
// sW 132 floats; frag reads are float4 at c=tx*4 / 64+tx*4 -> <=2-way conflicts (free).
#define BM 64
#define KC 32

__global__ __launch_bounds__(256) void sage_gemm(
    const float* __restrict__ agg, const float* __restrict__ hsrc,
    const float* __restrict__ Wl, const float* __restrict__ Wr,
    const float* __restrict__ bias, float* __restrict__ out,
    int relu_x, int add_res) {
    __shared__ __align__(16) float sA[KC][BM + 4];
    __shared__ __align__(16) float sX[KC][BM + 4];
    __shared__ __align__(16) float sWl[KC][D + 4];
    __shared__ __align__(16) float sWr[KC][D + 4];

    const int tid = threadIdx.x;
    const int tx = tid & 15;   // col group: cols tx*4..+3 and 64+tx*4..+3
    const int ty = tid >> 4;   // row group: rows ty*4..+3
    const int n0 = blockIdx.x * BM;

    float acc[4][8];
#pragma unroll
    for (int i = 0; i < 4; ++i)
#pragma unroll
        for (int j = 0; j < 8; ++j) acc[i][j] = 0.f;

    for (int kc0 = 0; kc0 < D; kc0 += KC) {
        // stage agg + hsrc chunk (64 rows x 32 k), transposed to k-major
#pragma unroll
        for (int it = 0; it < 2; ++it) {
            int idx = tid + it * 256;           // 512 float4s
            int r = idx >> 3, kq = idx & 7;
            int g = n0 + r;
            float4 va = make_float4(0.f, 0.f, 0.f, 0.f);
            float4 vx = va;
            if (g < NN) {
                va = *(const float4*)(agg + (size_t)g * D + kc0 + kq * 4);
                vx = *(const float4*)(hsrc + (size_t)g * D + kc0 + kq * 4);
                if (relu_x) {
                    vx.x = fmaxf(vx.x, 0.f); vx.y = fmaxf(vx.y, 0.f);
                    vx.z = fmaxf(vx.z, 0.f); vx.w = fmaxf(vx.w, 0.f);
                }
            }
            sA[kq * 4 + 0][r] = va.x; sA[kq * 4 + 1][r] = va.y;
            sA[kq * 4 + 2][r] = va.z; sA[kq * 4 + 3][r] = va.w;
            sX[kq * 4 + 0][r] = vx.x; sX[kq * 4 + 1][r] = vx.y;
            sX[kq * 4 + 2][r] = vx.z; sX[kq * 4 + 3][r] = vx.w;
        }
        // stage Wl + Wr chunk (128 o x 32 k), transposed to k-major
#pragma unroll
        for (int it = 0; it < 4; ++it) {
            int idx = tid + it * 256;           // 1024 float4s
            int o = idx >> 3, kq = idx & 7;
            float4 vl = *(const float4*)(Wl + o * D + kc0 + kq * 4);
            float4 vr = *(const float4*)(Wr + o * D + kc0 + kq * 4);
            sWl[kq * 4 + 0][o] = vl.x; sWl[kq * 4 + 1][o] = vl.y;
            sWl[kq * 4 + 2][o] = vl.z; sWl[kq * 4 + 3][o] = vl.w;
            sWr[kq * 4 + 0][o] = vr.x; sWr[kq * 4 + 1][o] = vr.y;
            sWr[kq * 4 + 2][o] = vr.z; sWr[kq * 4 + 3][o] = vr.w;
        }
        __syncthreads();

#pragma unroll
        for (int k = 0; k < KC; ++k) {
            float4 av = *(const float4*)&sA[k][ty * 4];
            float4 xv = *(const float4*)&sX[k][ty * 4];
            float4 wl0 = *(const float4*)&sWl[k][tx * 4];
            float4 wl1 = *(const float4*)&sWl[k][64 + tx * 4];
            float4 wr0 = *(const float4*)&sWr[k][tx * 4];
            float4 wr1 = *(const float4*)&sWr[k][64 + tx * 4];
            float avf[4] = {av.x, av.y, av.z, av.w};
            float xvf[4] = {xv.x, xv.y, xv.z, xv.w};
            float wlf[8] = {wl0.x, wl0.y, wl0.z, wl0.w, wl1.x, wl1.y, wl1.z, wl1.w};
            float wrf[8] = {wr0.x, wr0.y, wr0.z, wr0.w, wr1.x, wr1.y, wr1.z, wr1.w};
#pragma unroll
            for (int i = 0; i < 4; ++i)
#pragma unroll
                for (int j = 0; j < 8; ++j)
                    acc[i][j] += avf[i] * wlf[j] + xvf[i] * wrf[j];
        }
        __syncthreads();
    }

    // epilogue: bias (+ residual), in-place-safe (block owns its rows)
    float4 b0 = *(const float4*)(bias + tx * 4);
    float4 b1 = *(const float4*)(bias + 64 + tx * 4);
#pragma unroll
    for (int i = 0; i < 4; ++i) {
        int g = n0 + ty * 4 + i;
        if (g < NN) {
            float4 r0, r1;
            r0.x = acc[i][0] + b0.x; r0.y = acc[i][1] + b0.y;
            r0.z = acc[i][2] + b0.z; r0.w = acc[i][3] + b0.w;
            r1.x = acc[i][4] + b1.x; r1.y = acc[i][5] + b1.y;
            r1.z = acc[i][6] + b1.z; r1.w = acc[i][7] + b1.w;
            if (add_res) {
                float4 s0 = *(const float4*)(hsrc + (size_t)g * D + tx * 4);
                float4 s1 = *(const float4*)(hsrc + (size_t)g * D + 64 + tx * 4);
                r0.x += s0.x; r0.y += s0.y; r0.z += s0.z; r0.w += s0.w;
                r1.x += s1.x; r1.y += s1.y; r1.z += s1.z; r1.w += s1.w;
            }
            *(float4*)(out + (size_t)g * D + tx * 4) = r0;
            *(float4*)(out + (size_t)g * D + 64 + tx * 4) = r1;
        }
    }
}

// ---------------- launch ----------------

extern "C" void kernel_launch(void* const* d_in, const int* in_sizes, int n_in,
                              void* d_out, int out_size, void* d_ws, size_t ws_size,
                              hipStream_t stream) {
    const float* x    = (const float*)d_in[0];
    const int*   erow = (const int*)d_in[1];
    const int*   ecol = (const int*)d_in[2];
    const float* Wl0 = (const float*)d_in[3];
    const float* Wr0 = (const float*)d_in[4];
    const float* b0  = (const float*)d_in[5];
    const float* Wl1 = (const float*)d_in[6];
    const float* Wr1 = (const float*)d_in[7];
    const float* b1  = (const float*)d_in[8];
    const float* Wl2 = (const float*)d_in[9];
    const float* Wr2 = (const float*)d_in[10];
    const float* b2  = (const float*)d_in[11];

    char* ws = (char*)d_ws;
    size_t off = 0;
    auto carve = [&](size_t bytes) -> void* {
        void* p = ws + off;
        off = (off + bytes + 255) & ~(size_t)255;
        return p;
    };
    int*   deg     = (int*)carve((size_t)NN * 4);
    int*   offsets = (int*)carve((size_t)(NN + 1) * 4);
    int*   cursor  = (int*)carve((size_t)NN * 4);
    int*   csr_col = (int*)carve((size_t)NE * 4);
    float* agg     = (float*)carve((size_t)NN * D * 4);
    float* bufA    = (float*)carve((size_t)NN * D * 4);
    (void)ws_size; (void)in_sizes; (void)n_in; (void)out_size;

    float* outp = (float*)d_out;

    hipMemsetAsync(deg, 0, (size_t)NN * 4, stream);
    count_deg<<<(NE + 255) / 256, 256, 0, stream>>>(erow, deg, NE);
    scan_offsets<<<1, 1024, 0, stream>>>(deg, offsets, cursor, NN);
    fill_csr<<<(NE + 255) / 256, 256, 0, stream>>>(erow, ecol, cursor, csr_col, NE);

    const int agrid = NN / 4;               // 12500, exact
    const int ggrid = (NN + BM - 1) / BM;   // 782

    // layer 0
    aggregate<<<agrid, 256, 0, stream>>>(x, offsets, csr_col, agg, 0);
    sage_gemm<<<ggrid, 256, 0, stream>>>(agg, x, Wl0, Wr0, b0, bufA, 0, 0);
    // layer 1 (relu input, residual, in-place)
    aggregate<<<agrid, 256, 0, stream>>>(bufA, offsets, csr_col, agg, 1);
    sage_gemm<<<ggrid, 256, 0, stream>>>(agg, bufA, Wl1, Wr1, b1, bufA, 1, 1);
    // layer 2 (relu input, residual, to d_out)
    aggregate<<<agrid, 256, 0, stream>>>(bufA, offsets, csr_col, agg, 1);
    sage_gemm<<<ggrid, 256, 0, stream>>>(agg, bufA, Wl2, Wr2, b2, outp, 1, 1);
}

// Round 2
// 444.089 us; speedup vs baseline: 2.0119x; 2.0119x over previous
//
#include <hip/hip_runtime.h>

#define NN 50000
#define NE 800000
#define D  128

typedef _Float16 f16;
typedef _Float16 f16x2 __attribute__((ext_vector_type(2)));
typedef _Float16 f16x4 __attribute__((ext_vector_type(4)));
typedef _Float16 f16x8 __attribute__((ext_vector_type(8)));
typedef float f32x4 __attribute__((ext_vector_type(4)));

// ---------------- converts ----------------

__global__ void convert_f32_f16(const float* __restrict__ src, f16* __restrict__ dst, int n4) {
    int i = blockIdx.x * blockDim.x + threadIdx.x;
    if (i < n4) {
        float4 v = ((const float4*)src)[i];
        f16x4 o = {(f16)v.x, (f16)v.y, (f16)v.z, (f16)v.w};
        ((f16x4*)dst)[i] = o;
    }
}

// 6 weight matrices (128x128 each = 4096 float4s), blockIdx.y selects matrix.
__global__ void convert_w6(const float* s0, const float* s1, const float* s2,
                           const float* s3, const float* s4, const float* s5,
                           f16* d0, f16* d1, f16* d2, f16* d3, f16* d4, f16* d5) {
    const float* s; f16* d;
    switch (blockIdx.y) {
        case 0: s = s0; d = d0; break; case 1: s = s1; d = d1; break;
        case 2: s = s2; d = d2; break; case 3: s = s3; d = d3; break;
        case 4: s = s4; d = d4; break; default: s = s5; d = d5; break;
    }
    int i = blockIdx.x * blockDim.x + threadIdx.x;   // 0..4095
    float4 v = ((const float4*)s)[i];
    f16x4 o = {(f16)v.x, (f16)v.y, (f16)v.z, (f16)v.w};
    ((f16x4*)d)[i] = o;
}

// ---------------- CSR build ----------------

__global__ void count_deg(const int* __restrict__ row, int* __restrict__ deg, int e) {
    int i = blockIdx.x * blockDim.x + threadIdx.x;
    if (i < e) atomicAdd(&deg[row[i]], 1);
}

// hierarchical scan: partial sums -> tiny scan -> final per-block scan
__global__ void scan_partial(const int* __restrict__ deg, int* __restrict__ bsum, int n) {
    __shared__ int s[1024];
    int i = blockIdx.x * 1024 + threadIdx.x;
    s[threadIdx.x] = (i < n) ? deg[i] : 0;
    __syncthreads();
    for (int off = 512; off > 0; off >>= 1) {
        if (threadIdx.x < off) s[threadIdx.x] += s[threadIdx.x + off];
        __syncthreads();
    }
    if (threadIdx.x == 0) bsum[blockIdx.x] = s[0];
}

__global__ void scan_bsum(int* __restrict__ bsum, int nb) {
    if (threadIdx.x == 0 && blockIdx.x == 0) {
        int acc = 0;
        for (int b = 0; b < nb; ++b) { int v = bsum[b]; bsum[b] = acc; acc += v; }
    }
}

__global__ void scan_final(const int* __restrict__ deg, const int* __restrict__ bsum,
                           int* __restrict__ offsets, int* __restrict__ cursor, int n) {
    __shared__ int s[1024];
    int i = blockIdx.x * 1024 + threadIdx.x;
    int v = (i < n) ? deg[i] : 0;
    s[threadIdx.x] = v;
    __syncthreads();
    for (int off = 1; off < 1024; off <<= 1) {
        int t = (threadIdx.x >= (unsigned)off) ? s[threadIdx.x - off] : 0;
        __syncthreads();
        s[threadIdx.x] += t;
        __syncthreads();
    }
    if (i < n) {
        int incl = s[threadIdx.x] + bsum[blockIdx.x];
        offsets[i + 1] = incl;
        cursor[i] = incl - v;
        if (i == 0) offsets[0] = 0;
    }
}

__global__ void fill_csr(const int* __restrict__ row, const int* __restrict__ col,
                         int* __restrict__ cursor, int* __restrict__ csr_col, int e) {
    int i = blockIdx.x * blockDim.x + threadIdx.x;
    if (i < e) {
        int p = atomicAdd(&cursor[row[i]], 1);
        csr_col[p] = col[i];
    }
}

// ---------------- mean aggregation (f16 gather, fp32 accumulate) ----------------
// One 64-lane wave per node; lane t holds features [2t, 2t+1] (f16x2 = 4B/lane,
// 256B coalesced per gathered row). Unroll-4 for gather ILP.
__global__ __launch_bounds__(256) void aggregate_f16(
    const f16* __restrict__ h, const int* __restrict__ offsets,
    const int* __restrict__ csr_col, f16* __restrict__ agg) {
    int node = blockIdx.x * 4 + (threadIdx.x >> 6);
    int t = threadIdx.x & 63;
    if (node >= NN) return;
    int s0 = offsets[node], e0 = offsets[node + 1];
    float ax = 0.f, ay = 0.f;
    int j = s0;
    for (; j + 4 <= e0; j += 4) {
        int c0 = csr_col[j], c1 = csr_col[j + 1], c2 = csr_col[j + 2], c3 = csr_col[j + 3];
        f16x2 v0 = *((const f16x2*)(h + (size_t)c0 * D) + t);
        f16x2 v1 = *((const f16x2*)(h + (size_t)c1 * D) + t);
        f16x2 v2 = *((const f16x2*)(h + (size_t)c2 * D) + t);
        f16x2 v3 = *((const f16x2*)(h + (size_t)c3 * D) + t);
        ax += (float)v0.x + (float)v1.x + (float)v2.x + (float)v3.x;
        ay += (float)v0.y + (float)v1.y + (float)v2.y + (float)v3.y;
    }
    for (; j < e0; ++j) {
        int c = csr_col[j];
        f16x2 v = *((const f16x2*)(h + (size_t)c * D) + t);
        ax += (float)v.x;
        ay += (float)v.y;
    }
    float inv = 1.f / fmaxf((float)(e0 - s0), 1.f);
    f16x2 o = {(f16)(ax * inv), (f16)(ay * inv)};
    *((f16x2*)(agg + (size_t)node * D) + t) = o;
}

// ---------------- MFMA dual-GEMM + bias + residual + fused relu-f16 ----------------
// out[m][n] = sum_k agg[m][k]*Wl[n][k] + x[m][k]*Wr[n][k] + b[n] (+ res[m][n])
// next_hb[m][n] = f16(relu(out[m][n]))  (may alias xb: block only touches own rows)
// Per wave: 16-row x 128-col tile, K=128. A-frags in regs, B-frags streamed from
// L1/L2 (Wl+Wr = 64KB working set). No LDS, no barriers.
// mfma_f32_16x16x32_f16: A[m=lane&15][k=(lane>>4)*8+j]; B[n=lane&15][k=(lane>>4)*8+j];
// D: col n = lane&15, row m = (lane>>4)*4 + reg  (layout per m89/m120, dtype-indep).
__global__ __launch_bounds__(256) void sage_gemm_mfma(
    const f16* __restrict__ aggb, const f16* __restrict__ xb,
    const f16* __restrict__ Wl, const f16* __restrict__ Wr,
    const float* __restrict__ bias, const float* __restrict__ res,
    float* __restrict__ out, f16* __restrict__ next_hb,
    int add_res, int write_hb) {
    const int wave = threadIdx.x >> 6;
    const int lane = threadIdx.x & 63;
    const int lm = lane & 15;
    const int q  = lane >> 4;
    const int m0 = blockIdx.x * 64 + wave * 16;

    int row = m0 + lm;
    int rclamp = (row < NN) ? row : NN - 1;   // invalid rows' results are discarded

    f16x8 Aa[4], Ax[4];
    const f16* arow = aggb + (size_t)rclamp * D + q * 8;
    const f16* xrow = xb  + (size_t)rclamp * D + q * 8;
#pragma unroll
    for (int ks = 0; ks < 4; ++ks) {
        Aa[ks] = *(const f16x8*)(arow + ks * 32);
        Ax[ks] = *(const f16x8*)(xrow + ks * 32);
    }

    f32x4 acc[8];
#pragma unroll
    for (int nt = 0; nt < 8; ++nt) {
        const f16* wlrow = Wl + (size_t)(nt * 16 + lm) * D + q * 8;
        const f16* wrrow = Wr + (size_t)(nt * 16 + lm) * D + q * 8;
        f32x4 a = {0.f, 0.f, 0.f, 0.f};
#pragma unroll
        for (int ks = 0; ks < 4; ++ks) {
            f16x8 bl = *(const f16x8*)(wlrow + ks * 32);
            a = __builtin_amdgcn_mfma_f32_16x16x32_f16(Aa[ks], bl, a, 0, 0, 0);
        }
#pragma unroll
        for (int ks = 0; ks < 4; ++ks) {
            f16x8 br = *(const f16x8*)(wrrow + ks * 32);
            a = __builtin_amdgcn_mfma_f32_16x16x32_f16(Ax[ks], br, a, 0, 0, 0);
        }
        acc[nt] = a;
    }

    // epilogue
#pragma unroll
    for (int nt = 0; nt < 8; ++nt) {
        int n = nt * 16 + lm;
        float bval = bias[n];
#pragma unroll
        for (int r = 0; r < 4; ++r) {
            int m = m0 + q * 4 + r;
            if (m < NN) {
                size_t idx = (size_t)m * D + n;
                float v = acc[nt][r] + bval;
                if (add_res) v += res[idx];
                out[idx] = v;
                if (write_hb) next_hb[idx] = (f16)fmaxf(v, 0.f);
            }
        }
    }
}

// ---------------- launch ----------------

extern "C" void kernel_launch(void* const* d_in, const int* in_sizes, int n_in,
                              void* d_out, int out_size, void* d_ws, size_t ws_size,
                              hipStream_t stream) {
    const float* x    = (const float*)d_in[0];
    const int*   erow = (const int*)d_in[1];
    const int*   ecol = (const int*)d_in[2];
    const float* Wl0 = (const float*)d_in[3];
    const float* Wr0 = (const float*)d_in[4];
    const float* b0  = (const float*)d_in[5];
    const float* Wl1 = (const float*)d_in[6];
    const float* Wr1 = (const float*)d_in[7];
    const float* b1  = (const float*)d_in[8];
    const float* Wl2 = (const float*)d_in[9];
    const float* Wr2 = (const float*)d_in[10];
    const float* b2  = (const float*)d_in[11];

    char* ws = (char*)d_ws;
    size_t off = 0;
    auto carve = [&](size_t bytes) -> void* {
        void* p = ws + off;
        off = (off + bytes + 255) & ~(size_t)255;
        return p;
    };
    int*   deg     = (int*)carve((size_t)NN * 4);
    int*   offsets = (int*)carve((size_t)(NN + 1) * 4);
    int*   cursor  = (int*)carve((size_t)NN * 4);
    int*   bsum    = (int*)carve(64 * 4);
    int*   csr_col = (int*)carve((size_t)NE * 4);
    f16*   hb      = (f16*)carve((size_t)NN * D * 2);
    f16*   aggb    = (f16*)carve((size_t)NN * D * 2);
    float* bufA    = (float*)carve((size_t)NN * D * 4);
    f16*   wl0 = (f16*)carve(D * D * 2); f16* wr0 = (f16*)carve(D * D * 2);
    f16*   wl1 = (f16*)carve(D * D * 2); f16* wr1 = (f16*)carve(D * D * 2);
    f16*   wl2 = (f16*)carve(D * D * 2); f16* wr2 = (f16*)carve(D * D * 2);
    (void)ws_size; (void)in_sizes; (void)n_in; (void)out_size;

    float* outp = (float*)d_out;

    // converts
    convert_f32_f16<<<(NN * D / 4 + 255) / 256, 256, 0, stream>>>(x, hb, NN * D / 4);
    dim3 wgrid(16, 6);
    convert_w6<<<wgrid, 256, 0, stream>>>(Wl0, Wr0, Wl1, Wr1, Wl2, Wr2,
                                          wl0, wr0, wl1, wr1, wl2, wr2);

    // CSR build
    hipMemsetAsync(deg, 0, (size_t)NN * 4, stream);
    count_deg<<<(NE + 255) / 256, 256, 0, stream>>>(erow, deg, NE);
    const int nsb = (NN + 1023) / 1024;   // 49
    scan_partial<<<nsb, 1024, 0, stream>>>(deg, bsum, NN);
    scan_bsum<<<1, 64, 0, stream>>>(bsum, nsb);
    scan_final<<<nsb, 1024, 0, stream>>>(deg, bsum, offsets, cursor, NN);
    fill_csr<<<(NE + 255) / 256, 256, 0, stream>>>(erow, ecol, cursor, csr_col, NE);

    const int agrid = NN / 4;               // 12500, exact
    const int ggrid = (NN + 63) / 64;       // 782

    // layer 0: out = agg(x)@Wl0^T + x@Wr0^T + b0 -> bufA; hb <- f16(relu(bufA))
    aggregate_f16<<<agrid, 256, 0, stream>>>(hb, offsets, csr_col, aggb);
    sage_gemm_mfma<<<ggrid, 256, 0, stream>>>(aggb, hb, wl0, wr0, b0, nullptr,
                                              bufA, hb, 0, 1);
    // layer 1: out = agg(h)@Wl1^T + h@Wr1^T + b1 + bufA -> bufA (in-place); hb <- relu
    aggregate_f16<<<agrid, 256, 0, stream>>>(hb, offsets, csr_col, aggb);
    sage_gemm_mfma<<<ggrid, 256, 0, stream>>>(aggb, hb, wl1, wr1, b1, bufA,
                                              bufA, hb, 1, 1);
    // layer 2: out = agg(h)@Wl2^T + h@Wr2^T + b2 + bufA -> d_out
    aggregate_f16<<<agrid, 256, 0, stream>>>(hb, offsets, csr_col, aggb);
    sage_gemm_mfma<<<ggrid, 256, 0, stream>>>(aggb, hb, wl2, wr2, b2, bufA,
                                              outp, nullptr, 1, 0);
}

// Round 3
// 338.166 us; speedup vs baseline: 2.6421x; 1.3132x over previous
//
#include <hip/hip_runtime.h>

#define NN 50000
#define NE 800000
#define D  128

typedef _Float16 f16;
typedef _Float16 f16x2 __attribute__((ext_vector_type(2)));
typedef _Float16 f16x4 __attribute__((ext_vector_type(4)));
typedef _Float16 f16x8 __attribute__((ext_vector_type(8)));
typedef float f32x4 __attribute__((ext_vector_type(4)));

// ---------------- converts ----------------

__global__ void convert_f32_f16(const float* __restrict__ src, f16* __restrict__ dst, int n4) {
    int i = blockIdx.x * blockDim.x + threadIdx.x;
    if (i < n4) {
        float4 v = ((const float4*)src)[i];
        f16x4 o = {(f16)v.x, (f16)v.y, (f16)v.z, (f16)v.w};
        ((f16x4*)dst)[i] = o;
    }
}

__global__ void convert_w6(const float* s0, const float* s1, const float* s2,
                           const float* s3, const float* s4, const float* s5,
                           f16* d0, f16* d1, f16* d2, f16* d3, f16* d4, f16* d5) {
    const float* s; f16* d;
    switch (blockIdx.y) {
        case 0: s = s0; d = d0; break; case 1: s = s1; d = d1; break;
        case 2: s = s2; d = d2; break; case 3: s = s3; d = d3; break;
        case 4: s = s4; d = d4; break; default: s = s5; d = d5; break;
    }
    int i = blockIdx.x * blockDim.x + threadIdx.x;   // 0..4095
    float4 v = ((const float4*)s)[i];
    f16x4 o = {(f16)v.x, (f16)v.y, (f16)v.z, (f16)v.w};
    ((f16x4*)d)[i] = o;
}

// ---------------- CSR build (atomic-free fill via rank) ----------------

__global__ void count_deg_rank(const int* __restrict__ row, int* __restrict__ deg,
                               int* __restrict__ rank, int e) {
    int i = blockIdx.x * blockDim.x + threadIdx.x;
    if (i < e) rank[i] = atomicAdd(&deg[row[i]], 1);
}

__global__ void scan_partial(const int* __restrict__ deg, int* __restrict__ bsum, int n) {
    __shared__ int s[1024];
    int i = blockIdx.x * 1024 + threadIdx.x;
    s[threadIdx.x] = (i < n) ? deg[i] : 0;
    __syncthreads();
    for (int off = 512; off > 0; off >>= 1) {
        if (threadIdx.x < off) s[threadIdx.x] += s[threadIdx.x + off];
        __syncthreads();
    }
    if (threadIdx.x == 0) bsum[blockIdx.x] = s[0];
}

__global__ void scan_bsum(int* __restrict__ bsum, int nb) {
    if (threadIdx.x == 0 && blockIdx.x == 0) {
        int acc = 0;
        for (int b = 0; b < nb; ++b) { int v = bsum[b]; bsum[b] = acc; acc += v; }
    }
}

__global__ void scan_final(const int* __restrict__ deg, const int* __restrict__ bsum,
                           int* __restrict__ offsets, int n) {
    __shared__ int s[1024];
    int i = blockIdx.x * 1024 + threadIdx.x;
    int v = (i < n) ? deg[i] : 0;
    s[threadIdx.x] = v;
    __syncthreads();
    for (int off = 1; off < 1024; off <<= 1) {
        int t = (threadIdx.x >= (unsigned)off) ? s[threadIdx.x - off] : 0;
        __syncthreads();
        s[threadIdx.x] += t;
        __syncthreads();
    }
    if (i < n) {
        int incl = s[threadIdx.x] + bsum[blockIdx.x];
        offsets[i + 1] = incl;
        if (i == 0) offsets[0] = 0;
    }
}

__global__ void fill_csr(const int* __restrict__ row, const int* __restrict__ col,
                         const int* __restrict__ rank, const int* __restrict__ offsets,
                         int* __restrict__ csr_col, int e) {
    int i = blockIdx.x * blockDim.x + threadIdx.x;
    if (i < e) {
        int p = offsets[row[i]] + rank[i];
        csr_col[p] = col[i];
    }
}

// ---------------- mean aggregation (f16 gather, fp32 accumulate) ----------------
// One 64-lane wave per node; lane t holds features [2t, 2t+1]. Unroll-8 for ILP.
__global__ __launch_bounds__(256) void aggregate_f16(
    const f16* __restrict__ h, const int* __restrict__ offsets,
    const int* __restrict__ csr_col, f16* __restrict__ agg, int relu_in) {
    int node = blockIdx.x * 4 + (threadIdx.x >> 6);
    int t = threadIdx.x & 63;
    if (node >= NN) return;
    int s0 = offsets[node], e0 = offsets[node + 1];
    float ax = 0.f, ay = 0.f;
    int j = s0;
    for (; j + 8 <= e0; j += 8) {
        int c[8];
#pragma unroll
        for (int u = 0; u < 8; ++u) c[u] = csr_col[j + u];
        f16x2 v[8];
#pragma unroll
        for (int u = 0; u < 8; ++u) v[u] = *((const f16x2*)(h + (size_t)c[u] * D) + t);
#pragma unroll
        for (int u = 0; u < 8; ++u) {
            float vx = (float)v[u].x, vy = (float)v[u].y;
            if (relu_in) { vx = fmaxf(vx, 0.f); vy = fmaxf(vy, 0.f); }
            ax += vx; ay += vy;
        }
    }
    for (; j < e0; ++j) {
        int c = csr_col[j];
        f16x2 v = *((const f16x2*)(h + (size_t)c * D) + t);
        float vx = (float)v.x, vy = (float)v.y;
        if (relu_in) { vx = fmaxf(vx, 0.f); vy = fmaxf(vy, 0.f); }
        ax += vx; ay += vy;
    }
    float inv = 1.f / fmaxf((float)(e0 - s0), 1.f);
    f16x2 o = {(f16)(ax * inv), (f16)(ay * inv)};
    *((f16x2*)(agg + (size_t)node * D) + t) = o;
}

// ---------------- MFMA dual-GEMM, LDS-staged weights ----------------
// out[m][n] = sum_k agg[m][k]*Wl[n][k] + relu?(x[m][k])*Wr[n][k] + b[n] (+ x[m][n])
// Block: 4 waves, 64 rows; each wave a 16x128 tile. Weights staged in LDS in
// 2 K-phases (Wl+Wr half-K = 32KB + pad). B-frags via ds_read_b128; row pad of
// 8 f16 (16B) makes row stride 144B -> <=2-way bank aliasing (free, m136).
#define WPAD 72   // 64 + 8 f16

__global__ __launch_bounds__(256, 4) void sage_gemm_mfma(
    const f16* __restrict__ aggb, const f16* __restrict__ xb,
    const f16* __restrict__ Wl, const f16* __restrict__ Wr,
    const float* __restrict__ bias, float* __restrict__ outf,
    f16* __restrict__ outh, int relu_x, int add_res) {
    __shared__ f16 sW[2][128][WPAD];   // [mat][n][k-in-half], 36864 B

    const int tid  = threadIdx.x;
    const int wave = tid >> 6;
    const int lane = tid & 63;
    const int lm = lane & 15;
    const int q  = lane >> 4;
    const int mt = blockIdx.x * 64 + wave * 16;

    int row = mt + lm;
    int rclamp = (row < NN) ? row : NN - 1;   // invalid rows discarded in epilogue

    // A fragments (full K), relu on x inline
    f16x8 Aa[4], Ax[4];
    const f16* arow = aggb + (size_t)rclamp * D + q * 8;
    const f16* xrow = xb  + (size_t)rclamp * D + q * 8;
#pragma unroll
    for (int ks = 0; ks < 4; ++ks) {
        Aa[ks] = *(const f16x8*)(arow + ks * 32);
        f16x8 v = *(const f16x8*)(xrow + ks * 32);
        if (relu_x) {
#pragma unroll
            for (int u = 0; u < 8; ++u) v[u] = (v[u] > (f16)0) ? v[u] : (f16)0;
        }
        Ax[ks] = v;
    }

    f32x4 acc[8];
#pragma unroll
    for (int nt = 0; nt < 8; ++nt) acc[nt] = (f32x4){0.f, 0.f, 0.f, 0.f};

    for (int p = 0; p < 2; ++p) {
        __syncthreads();
        // stage Wl/Wr K-half: 2 mats x 128 n x 8 chunks of 16B = 2048 chunks
#pragma unroll
        for (int it = 0; it < 8; ++it) {
            int idx = tid + it * 256;
            int mat = idx >> 10;
            int n   = (idx >> 3) & 127;
            int c   = idx & 7;
            const f16* W = mat ? Wr : Wl;
            f16x8 v = *(const f16x8*)(W + n * D + p * 64 + c * 8);
            *(f16x8*)&sW[mat][n][c * 8] = v;
        }
        __syncthreads();

#pragma unroll
        for (int nt = 0; nt < 8; ++nt) {
#pragma unroll
            for (int k2 = 0; k2 < 2; ++k2) {
                f16x8 bl = *(const f16x8*)&sW[0][nt * 16 + lm][k2 * 32 + q * 8];
                acc[nt] = __builtin_amdgcn_mfma_f32_16x16x32_f16(Aa[p * 2 + k2], bl, acc[nt], 0, 0, 0);
                f16x8 br = *(const f16x8*)&sW[1][nt * 16 + lm][k2 * 32 + q * 8];
                acc[nt] = __builtin_amdgcn_mfma_f32_16x16x32_f16(Ax[p * 2 + k2], br, acc[nt], 0, 0, 0);
            }
        }
    }

    // epilogue: bias (+ f16 residual from xb). In-place outh==xb is safe:
    // each (m,n) is read & written by exactly one lane, rows owned by this wave.
#pragma unroll
    for (int nt = 0; nt < 8; ++nt) {
        int n = nt * 16 + lm;
        float bval = bias[n];
#pragma unroll
        for (int r = 0; r < 4; ++r) {
            int m = mt + q * 4 + r;
            if (m < NN) {
                size_t idx = (size_t)m * D + n;
                float v = acc[nt][r] + bval;
                if (add_res) v += (float)xb[idx];
                if (outh) outh[idx] = (f16)v;
                else      outf[idx] = v;
            }
        }
    }
}

// ---------------- launch ----------------

extern "C" void kernel_launch(void* const* d_in, const int* in_sizes, int n_in,
                              void* d_out, int out_size, void* d_ws, size_t ws_size,
                              hipStream_t stream) {
    const float* x    = (const float*)d_in[0];
    const int*   erow = (const int*)d_in[1];
    const int*   ecol = (const int*)d_in[2];
    const float* Wl0 = (const float*)d_in[3];
    const float* Wr0 = (const float*)d_in[4];
    const float* b0  = (const float*)d_in[5];
    const float* Wl1 = (const float*)d_in[6];
    const float* Wr1 = (const float*)d_in[7];
    const float* b1  = (const float*)d_in[8];
    const float* Wl2 = (const float*)d_in[9];
    const float* Wr2 = (const float*)d_in[10];
    const float* b2  = (const float*)d_in[11];

    char* ws = (char*)d_ws;
    size_t off = 0;
    auto carve = [&](size_t bytes) -> void* {
        void* p = ws + off;
        off = (off + bytes + 255) & ~(size_t)255;
        return p;
    };
    int*   deg     = (int*)carve((size_t)NN * 4);
    int*   offsets = (int*)carve((size_t)(NN + 1) * 4);
    int*   bsum    = (int*)carve(64 * 4);
    int*   rank    = (int*)carve((size_t)NE * 4);
    int*   csr_col = (int*)carve((size_t)NE * 4);
    f16*   xf      = (f16*)carve((size_t)NN * D * 2);
    f16*   x1      = (f16*)carve((size_t)NN * D * 2);
    f16*   aggb    = (f16*)carve((size_t)NN * D * 2);
    f16*   wl0 = (f16*)carve(D * D * 2); f16* wr0 = (f16*)carve(D * D * 2);
    f16*   wl1 = (f16*)carve(D * D * 2); f16* wr1 = (f16*)carve(D * D * 2);
    f16*   wl2 = (f16*)carve(D * D * 2); f16* wr2 = (f16*)carve(D * D * 2);
    (void)ws_size; (void)in_sizes; (void)n_in; (void)out_size;

    float* outp = (float*)d_out;

    // converts
    convert_f32_f16<<<(NN * D / 4 + 255) / 256, 256, 0, stream>>>(x, xf, NN * D / 4);
    dim3 wgrid(16, 6);
    convert_w6<<<wgrid, 256, 0, stream>>>(Wl0, Wr0, Wl1, Wr1, Wl2, Wr2,
                                          wl0, wr0, wl1, wr1, wl2, wr2);

    // CSR build
    hipMemsetAsync(deg, 0, (size_t)NN * 4, stream);
    count_deg_rank<<<(NE + 255) / 256, 256, 0, stream>>>(erow, deg, rank, NE);
    const int nsb = (NN + 1023) / 1024;   // 49
    scan_partial<<<nsb, 1024, 0, stream>>>(deg, bsum, NN);
    scan_bsum<<<1, 64, 0, stream>>>(bsum, nsb);
    scan_final<<<nsb, 1024, 0, stream>>>(deg, bsum, offsets, NN);
    fill_csr<<<(NE + 255) / 256, 256, 0, stream>>>(erow, ecol, rank, offsets, csr_col, NE);

    const int agrid = NN / 4;               // 12500, exact
    const int ggrid = (NN + 63) / 64;       // 782

    // layer 0: x1 = agg(xf)@Wl0^T + xf@Wr0^T + b0   (f16 state, pre-relu)
    aggregate_f16<<<agrid, 256, 0, stream>>>(xf, offsets, csr_col, aggb, 0);
    sage_gemm_mfma<<<ggrid, 256, 0, stream>>>(aggb, xf, wl0, wr0, b0,
                                              nullptr, x1, 0, 0);
    // layer 1: x1 = agg(relu(x1))@Wl1^T + relu(x1)@Wr1^T + b1 + x1  (in place)
    aggregate_f16<<<agrid, 256, 0, stream>>>(x1, offsets, csr_col, aggb, 1);
    sage_gemm_mfma<<<ggrid, 256, 0, stream>>>(aggb, x1, wl1, wr1, b1,
                                              nullptr, x1, 1, 1);
    // layer 2: out = agg(relu(x1))@Wl2^T + relu(x1)@Wr2^T + b2 + x1  (fp32)
    aggregate_f16<<<agrid, 256, 0, stream>>>(x1, offsets, csr_col, aggb, 1);
    sage_gemm_mfma<<<ggrid, 256, 0, stream>>>(aggb, x1, wl2, wr2, b2,
                                              outp, nullptr, 1, 1);
}

// Round 4
// 289.232 us; speedup vs baseline: 3.0891x; 1.1692x over previous
//
#include <hip/hip_runtime.h>

#define NN 50000
#define NE 800000
#define D  128

typedef _Float16 f16;
typedef _Float16 f16x4 __attribute__((ext_vector_type(4)));
typedef _Float16 f16x8 __attribute__((ext_vector_type(8)));
typedef float f32x4 __attribute__((ext_vector_type(4)));
typedef unsigned short u16;

// ---------------- prep: all f32->f16 converts + deg zeroing, one kernel ----------------
// blocks [0,6250): x (1.6M float4s); [6250,6346): 6 weight mats; [6346,6542): zero deg
__global__ __launch_bounds__(256) void prep(
    const float* __restrict__ x, f16* __restrict__ xf,
    const float* w0, const float* w1, const float* w2,
    const float* w3, const float* w4, const float* w5,
    f16* d0, f16* d1, f16* d2, f16* d3, f16* d4, f16* d5,
    int* __restrict__ deg) {
    int b = blockIdx.x;
    if (b < 6250) {
        int i = b * 256 + threadIdx.x;
        float4 v = ((const float4*)x)[i];
        f16x4 o = {(f16)v.x, (f16)v.y, (f16)v.z, (f16)v.w};
        ((f16x4*)xf)[i] = o;
    } else if (b < 6346) {
        int wb = b - 6250;
        int mat = wb >> 4;
        const float* s; f16* d;
        switch (mat) {
            case 0: s = w0; d = d0; break; case 1: s = w1; d = d1; break;
            case 2: s = w2; d = d2; break; case 3: s = w3; d = d3; break;
            case 4: s = w4; d = d4; break; default: s = w5; d = d5; break;
        }
        int i = (wb & 15) * 256 + threadIdx.x;   // 0..4095 float4
        float4 v = ((const float4*)s)[i];
        f16x4 o = {(f16)v.x, (f16)v.y, (f16)v.z, (f16)v.w};
        ((f16x4*)d)[i] = o;
    } else {
        int i = (b - 6346) * 256 + threadIdx.x;
        if (i < NN) deg[i] = 0;
    }
}

// ---------------- CSR build ----------------

__global__ __launch_bounds__(256) void count_deg_rank(
    const int* __restrict__ row, int* __restrict__ deg, u16* __restrict__ rank, int e) {
    int i = blockIdx.x * blockDim.x + threadIdx.x;
    if (i < e) rank[i] = (u16)atomicAdd(&deg[row[i]], 1);
}

__global__ void scan_partial(const int* __restrict__ deg, int* __restrict__ bsum, int n) {
    __shared__ int s[1024];
    int i = blockIdx.x * 1024 + threadIdx.x;
    s[threadIdx.x] = (i < n) ? deg[i] : 0;
    __syncthreads();
    for (int off = 512; off > 0; off >>= 1) {
        if (threadIdx.x < off) s[threadIdx.x] += s[threadIdx.x + off];
        __syncthreads();
    }
    if (threadIdx.x == 0) bsum[blockIdx.x] = s[0];
}

// final scan with inline exclusive block-prefix (wave-reduce over bsum)
__global__ void scan_final(const int* __restrict__ deg, const int* __restrict__ bsum,
                           int* __restrict__ offsets, int n, int nb) {
    __shared__ int s[1024];
    __shared__ int base;
    if (threadIdx.x < 64) {
        int t = threadIdx.x;
        int v = (t < nb && t < (int)blockIdx.x) ? bsum[t] : 0;
#pragma unroll
        for (int m = 1; m < 64; m <<= 1) v += __shfl_xor(v, m, 64);
        if (t == 0) base = v;
    }
    int i = blockIdx.x * 1024 + threadIdx.x;
    int dv = (i < n) ? deg[i] : 0;
    s[threadIdx.x] = dv;
    __syncthreads();
    for (int off = 1; off < 1024; off <<= 1) {
        int t = (threadIdx.x >= (unsigned)off) ? s[threadIdx.x - off] : 0;
        __syncthreads();
        s[threadIdx.x] += t;
        __syncthreads();
    }
    if (i < n) {
        offsets[i + 1] = s[threadIdx.x] + base;
        if (i == 0) offsets[0] = 0;
    }
}

__global__ __launch_bounds__(256) void fill_csr(
    const int* __restrict__ row, const int* __restrict__ col,
    const u16* __restrict__ rank, const int* __restrict__ offsets,
    u16* __restrict__ csr_col, int e) {
    int i = blockIdx.x * blockDim.x + threadIdx.x;
    if (i < e) {
        int p = offsets[row[i]] + (int)rank[i];
        csr_col[p] = (u16)col[i];
    }
}

// ---------------- mean aggregation ----------------
// One wave per node. Lane = (sub, fl): sub = lane>>4 is the edge slot (4 edges
// in parallel), fl = lane&15 the feature octet. Each load is f16x8 (16B/lane,
// 1KB/wave-instr). Unroll 2 -> 2KB in flight/wave. Accumulate fp32 via fma_mix
// pattern; final 2-round shuffle reduction across subs, write by sub==0 lanes.
template<int RELU>
__global__ __launch_bounds__(256) void aggregate_f16(
    const f16* __restrict__ h, const int* __restrict__ offsets,
    const u16* __restrict__ csr, f16* __restrict__ agg) {
    int node = blockIdx.x * 4 + (threadIdx.x >> 6);
    int lane = threadIdx.x & 63;
    int sub = lane >> 4, fl = lane & 15;
    int s0 = offsets[node], e0 = offsets[node + 1];
    int deg = e0 - s0;

    float acc[8];
#pragma unroll
    for (int u = 0; u < 8; ++u) acc[u] = 0.f;

    int j = s0 + sub;

#define ACCUM(cidx)                                                        \
    do {                                                                   \
        f16x8 v = *(const f16x8*)(h + (size_t)(cidx) * D + fl * 8);        \
        if (RELU) {                                                        \
            _Pragma("unroll")                                              \
            for (int u = 0; u < 8; ++u)                                    \
                v[u] = (v[u] < (f16)0) ? (f16)0 : v[u];                    \
        }                                                                  \
        _Pragma("unroll")                                                  \
        for (int u = 0; u < 8; ++u)                                        \
            acc[u] = fmaf((float)v[u], 1.0f, acc[u]);                      \
    } while (0)

    for (int it = deg >> 3; it > 0; --it, j += 8) {
        int c0 = csr[j];
        int c1 = csr[j + 4];
        f16x8 v0 = *(const f16x8*)(h + (size_t)c0 * D + fl * 8);
        f16x8 v1 = *(const f16x8*)(h + (size_t)c1 * D + fl * 8);
        if (RELU) {
#pragma unroll
            for (int u = 0; u < 8; ++u) {
                v0[u] = (v0[u] < (f16)0) ? (f16)0 : v0[u];
                v1[u] = (v1[u] < (f16)0) ? (f16)0 : v1[u];
            }
        }
#pragma unroll
        for (int u = 0; u < 8; ++u) {
            acc[u] = fmaf((float)v0[u], 1.0f, acc[u]);
            acc[u] = fmaf((float)v1[u], 1.0f, acc[u]);
        }
    }
    if (deg & 4) {
        int c = csr[j];
        ACCUM(c);
        j += 4;
    }
    if (sub < (deg & 3)) {
        int c = csr[j];
        ACCUM(c);
    }
#undef ACCUM

    // reduce across the 4 edge slots (lanes l, l^16, l^32, l^48)
#pragma unroll
    for (int u = 0; u < 8; ++u) {
        acc[u] += __shfl_xor(acc[u], 16, 64);
        acc[u] += __shfl_xor(acc[u], 32, 64);
    }
    if (sub == 0) {
        float inv = 1.f / fmaxf((float)deg, 1.f);
        f16x8 o;
#pragma unroll
        for (int u = 0; u < 8; ++u) o[u] = (f16)(acc[u] * inv);
        *((f16x8*)(agg + (size_t)node * D) + fl) = o;
    }
}

// ---------------- MFMA dual-GEMM, LDS-staged weights ----------------
#define WPAD 72   // 64 + 8 f16 pad -> 144B row stride, <=2-way bank aliasing

template<int RELU_X, int ADD_RES, int OUT_F32>
__global__ __launch_bounds__(256, 4) void sage_gemm_mfma(
    const f16* __restrict__ aggb, const f16* __restrict__ xb,
    const f16* __restrict__ Wl, const f16* __restrict__ Wr,
    const float* __restrict__ bias, float* __restrict__ outf,
    f16* __restrict__ outh) {
    __shared__ f16 sW[2][128][WPAD];   // 36864 B

    const int tid  = threadIdx.x;
    const int wave = tid >> 6;
    const int lane = tid & 63;
    const int lm = lane & 15;
    const int q  = lane >> 4;
    const int mt = blockIdx.x * 64 + wave * 16;

    int row = mt + lm;
    int rclamp = (row < NN) ? row : NN - 1;

    f16x8 Aa[4], Ax[4];
    const f16* arow = aggb + (size_t)rclamp * D + q * 8;
    const f16* xrow = xb  + (size_t)rclamp * D + q * 8;
#pragma unroll
    for (int ks = 0; ks < 4; ++ks) {
        Aa[ks] = *(const f16x8*)(arow + ks * 32);
        f16x8 v = *(const f16x8*)(xrow + ks * 32);
        if (RELU_X) {
#pragma unroll
            for (int u = 0; u < 8; ++u) v[u] = (v[u] < (f16)0) ? (f16)0 : v[u];
        }
        Ax[ks] = v;
    }

    f32x4 acc[8];
#pragma unroll
    for (int nt = 0; nt < 8; ++nt) acc[nt] = (f32x4){0.f, 0.f, 0.f, 0.f};

    for (int p = 0; p < 2; ++p) {
        __syncthreads();
#pragma unroll
        for (int it = 0; it < 8; ++it) {
            int idx = tid + it * 256;
            int mat = idx >> 10;
            int n   = (idx >> 3) & 127;
            int c   = idx & 7;
            const f16* W = mat ? Wr : Wl;
            f16x8 v = *(const f16x8*)(W + n * D + p * 64 + c * 8);
            *(f16x8*)&sW[mat][n][c * 8] = v;
        }
        __syncthreads();

#pragma unroll
        for (int nt = 0; nt < 8; ++nt) {
#pragma unroll
            for (int k2 = 0; k2 < 2; ++k2) {
                f16x8 bl = *(const f16x8*)&sW[0][nt * 16 + lm][k2 * 32 + q * 8];
                acc[nt] = __builtin_amdgcn_mfma_f32_16x16x32_f16(Aa[p * 2 + k2], bl, acc[nt], 0, 0, 0);
                f16x8 br = *(const f16x8*)&sW[1][nt * 16 + lm][k2 * 32 + q * 8];
                acc[nt] = __builtin_amdgcn_mfma_f32_16x16x32_f16(Ax[p * 2 + k2], br, acc[nt], 0, 0, 0);
            }
        }
    }

    // epilogue: bias (+ f16 residual from xb). In-place outh==xb is safe.
#pragma unroll
    for (int nt = 0; nt < 8; ++nt) {
        int n = nt * 16 + lm;
        float bval = bias[n];
#pragma unroll
        for (int r = 0; r < 4; ++r) {
            int m = mt + q * 4 + r;
            if (m < NN) {
                size_t idx = (size_t)m * D + n;
                float v = acc[nt][r] + bval;
                if (ADD_RES) v += (float)xb[idx];
                if (OUT_F32) outf[idx] = v;
                else         outh[idx] = (f16)v;
            }
        }
    }
}

// ---------------- launch ----------------

extern "C" void kernel_launch(void* const* d_in, const int* in_sizes, int n_in,
                              void* d_out, int out_size, void* d_ws, size_t ws_size,
                              hipStream_t stream) {
    const float* x    = (const float*)d_in[0];
    const int*   erow = (const int*)d_in[1];
    const int*   ecol = (const int*)d_in[2];
    const float* Wl0 = (const float*)d_in[3];
    const float* Wr0 = (const float*)d_in[4];
    const float* b0  = (const float*)d_in[5];
    const float* Wl1 = (const float*)d_in[6];
    const float* Wr1 = (const float*)d_in[7];
    const float* b1  = (const float*)d_in[8];
    const float* Wl2 = (const float*)d_in[9];
    const float* Wr2 = (const float*)d_in[10];
    const float* b2  = (const float*)d_in[11];

    char* ws = (char*)d_ws;
    size_t off = 0;
    auto carve = [&](size_t bytes) -> void* {
        void* p = ws + off;
        off = (off + bytes + 255) & ~(size_t)255;
        return p;
    };
    int*   deg     = (int*)carve((size_t)NN * 4);
    int*   offsets = (int*)carve((size_t)(NN + 1) * 4);
    int*   bsum    = (int*)carve(64 * 4);
    u16*   rank    = (u16*)carve((size_t)NE * 2);
    u16*   csr_col = (u16*)carve((size_t)NE * 2);
    f16*   xf      = (f16*)carve((size_t)NN * D * 2);
    f16*   x1      = (f16*)carve((size_t)NN * D * 2);
    f16*   aggb    = (f16*)carve((size_t)NN * D * 2);
    f16*   wl0 = (f16*)carve(D * D * 2); f16* wr0 = (f16*)carve(D * D * 2);
    f16*   wl1 = (f16*)carve(D * D * 2); f16* wr1 = (f16*)carve(D * D * 2);
    f16*   wl2 = (f16*)carve(D * D * 2); f16* wr2 = (f16*)carve(D * D * 2);
    (void)ws_size; (void)in_sizes; (void)n_in; (void)out_size;

    float* outp = (float*)d_out;

    // prep: converts + deg zero (6250 + 96 + 196 blocks)
    prep<<<6542, 256, 0, stream>>>(x, xf, Wl0, Wr0, Wl1, Wr1, Wl2, Wr2,
                                   wl0, wr0, wl1, wr1, wl2, wr2, deg);

    // CSR build
    count_deg_rank<<<(NE + 255) / 256, 256, 0, stream>>>(erow, deg, rank, NE);
    const int nsb = (NN + 1023) / 1024;   // 49
    scan_partial<<<nsb, 1024, 0, stream>>>(deg, bsum, NN);
    scan_final<<<nsb, 1024, 0, stream>>>(deg, bsum, offsets, NN, nsb);
    fill_csr<<<(NE + 255) / 256, 256, 0, stream>>>(erow, ecol, rank, offsets, csr_col, NE);

    const int agrid = NN / 4;               // 12500, exact
    const int ggrid = (NN + 63) / 64;       // 782

    // layer 0: x1 = agg(xf)@Wl0^T + xf@Wr0^T + b0   (f16 state, pre-relu)
    aggregate_f16<0><<<agrid, 256, 0, stream>>>(xf, offsets, csr_col, aggb);
    sage_gemm_mfma<0, 0, 0><<<ggrid, 256, 0, stream>>>(aggb, xf, wl0, wr0, b0,
                                                       nullptr, x1);
    // layer 1: x1 = agg(relu(x1))@Wl1^T + relu(x1)@Wr1^T + b1 + x1  (in place)
    aggregate_f16<1><<<agrid, 256, 0, stream>>>(x1, offsets, csr_col, aggb);
    sage_gemm_mfma<1, 1, 0><<<ggrid, 256, 0, stream>>>(aggb, x1, wl1, wr1, b1,
                                                       nullptr, x1);
    // layer 2: out = agg(relu(x1))@Wl2^T + relu(x1)@Wr2^T + b2 + x1  (fp32)
    aggregate_f16<1><<<agrid, 256, 0, stream>>>(x1, offsets, csr_col, aggb);
    sage_gemm_mfma<1, 1, 1><<<ggrid, 256, 0, stream>>>(aggb, x1, wl2, wr2, b2,
                                                       outp, nullptr);
}